// Round 4
// baseline (52.327 us; speedup 1.0000x reference)
//
#include <hip/hip_runtime.h>

typedef float  f32x4 __attribute__((ext_vector_type(4)));
typedef short  s16x8 __attribute__((ext_vector_type(8)));
typedef unsigned int u32;
typedef unsigned short u16;

#define B_N   8
#define C_N   128
#define HW_N  4096
#define G_N   16
#define K_N   2048
#define O_N   256
#define BN    128

typedef const __attribute__((address_space(1))) u32 gbl_u32;
typedef __attribute__((address_space(3))) u32 lds_u32;

__device__ __forceinline__ u16 bf16_bits(float f) {
  u32 u = __builtin_bit_cast(u32, f);
  u32 lsb = (u >> 16) & 1u;
  u += 0x7fffu + lsb;               // round-to-nearest-even
  return (u16)(u >> 16);
}

// ---- prep: W2 f32 [256][2048] -> bf16, exact LDS image, 64 tiles of 16 KB ----
// tile t = g*4 + kq  (g = group, kq = K-quarter of 32 channels)
// within tile, fragment-major rows of 16B:
//   row = mtile*64 + lk*16 + lc   for element (m = mtile*16+lc,
//                                              k = g*128 + kq*32 + lk*8 + j)
// ds_read at (base + lane*16) is perfectly linear -> conflict-free, and
// global_load_lds (linear lane*16 dest) stages it with zero rearrangement.
__global__ void w2cvt_k(const float* __restrict__ W2, char* __restrict__ w2t) {
  int f = blockIdx.x * 256 + threadIdx.x;   // 65536 fragment-rows of 16B
  int tile = f >> 10;
  int r    = f & 1023;
  int mtile = r >> 6;
  int lk    = (r >> 4) & 3;
  int lc    = r & 15;
  int m  = mtile * 16 + lc;
  int k0 = (tile >> 2) * 128 + (tile & 3) * 32 + lk * 8;
  const f32x4* src = reinterpret_cast<const f32x4*>(W2 + (size_t)m * K_N + k0);
  f32x4 v0 = src[0], v1 = src[1];
  s16x8 p;
  p[0]=bf16_bits(v0[0]); p[1]=bf16_bits(v0[1]); p[2]=bf16_bits(v0[2]); p[3]=bf16_bits(v0[3]);
  p[4]=bf16_bits(v1[0]); p[5]=bf16_bits(v1[1]); p[6]=bf16_bits(v1[2]); p[7]=bf16_bits(v1[3]);
  *reinterpret_cast<s16x8*>(w2t + (size_t)f * 16) = p;
}

// ---- main fused kernel ----
// Block: 256 o x 128 px, 8 waves (4 wm x 2 wn), wave tile 64o x 64px.
// B-fragments in regs for whole K loop. A streamed through 4 LDS slots with
// counted-vmcnt pipeline (stage-ahead 3), raw barriers, NO drain in loop.
__launch_bounds__(512, 2)
__global__ void ccattn_main_k(const float* __restrict__ x,
                              const float* __restrict__ W1,
                              const float* __restrict__ b1,
                              const char* __restrict__ w2t,
                              const float* __restrict__ b2,
                              float* __restrict__ out) {
  __shared__ __align__(16) char Abuf[4][16384];   // 64 KB, quarter-group slots
  __shared__ u16   xT[BN * C_N];                  // 32 KB
  __shared__ float fmT[G_N][BN];                  // 8 KB

  const int tid = threadIdx.x;
  const int bid = blockIdx.x;
  const int b   = bid >> 5;
  const int px0 = (bid & 31) * BN;

  const int w  = tid >> 6;
  const int l  = tid & 63;

  // stage one 16 KB tile: per wave 2 x global_load_lds of 1 KB (linear dest)
  auto stage = [&](int tile, int slot) {
    const char* src = w2t + (size_t)tile * 16384 + w * 2048 + l * 16;
    char* dst = &Abuf[slot][w * 2048];
#pragma unroll
    for (int r = 0; r < 2; ++r)
      __builtin_amdgcn_global_load_lds((gbl_u32*)(src + r * 1024),
                                       (lds_u32*)(dst + r * 1024), 16, 0, 0);
  };
  // prologue: fill 3 slots (drained by the one syncthreads below)
  stage(0, 0);
  stage(1, 1);
  stage(2, 2);

  // ---- staging: xT (bf16 [px][c], swizzled) + fm ----
  {
    const float* xb = x + (size_t)b * C_N * HW_N + px0;
    const int px = tid & 127;
    const int cq = tid >> 7;             // 4 groups each
#pragma unroll
    for (int gg = 0; gg < 4; ++gg) {
      const int g  = cq * 4 + gg;
      const int c0 = g * 8;
      float v[8];
#pragma unroll
      for (int j = 0; j < 8; ++j) v[j] = xb[(size_t)(c0 + j) * HW_N + px];
      float s = b1[g];
#pragma unroll
      for (int j = 0; j < 8; ++j) s += v[j] * W1[g * 8 + j];
      fmT[g][px] = fmaxf(s, 0.0f);
      s16x8 p;
#pragma unroll
      for (int j = 0; j < 8; ++j) p[j] = (short)bf16_bits(v[j]);
      int byte = (px * 256 + c0 * 2) ^ ((px & 15) << 4);
      *reinterpret_cast<s16x8*>(reinterpret_cast<char*>(xT) + byte) = p;
    }
  }
  __syncthreads();   // once: xT/fm ready, slots 0-2 landed (full drain ok here)

  // ---- wave decomposition ----
  const int wm = w & 3;
  const int wn = w >> 2;
  const int lc = l & 15;
  const int lk = l >> 4;

  // ---- B-fragment register cache [ks][nf] (valid for every group) ----
  s16x8 bfr[4][4];
#pragma unroll
  for (int ks = 0; ks < 4; ++ks)
#pragma unroll
    for (int nf = 0; nf < 4; ++nf) {
      int px  = wn * 64 + nf * 16 + lc;
      int byte = (px * 256 + (ks * 32 + lk * 8) * 2) ^ ((px & 15) << 4);
      bfr[ks][nf] = *reinterpret_cast<const s16x8*>(
          reinterpret_cast<const char*>(xT) + byte);
    }

  f32x4 acc[4][4];
  const f32x4 Z = {0.f, 0.f, 0.f, 0.f};
#pragma unroll
  for (int mf = 0; mf < 4; ++mf)
#pragma unroll
    for (int nf = 0; nf < 4; ++nf) acc[mf][nf] = Z;

  const int fofs = lk * 256 + lc * 16;   // fragment offset within a 1KB mf-row

  // ---- main loop: 64 phases (16 groups x 4 K-quarters), counted vmcnt ----
#pragma unroll 1
  for (int g = 0; g < 16; ++g) {
    f32x4 P[4][4];
#pragma unroll
    for (int ks = 0; ks < 4; ++ks) {
      const int t = g * 4 + ks;          // phase index; slot = ks
      // wait: at most 2 stages (4 loads) outstanding => stage(t) has landed
      asm volatile("s_waitcnt vmcnt(4)" ::: "memory");
      __builtin_amdgcn_s_barrier();      // raw barrier, no drain
      // prefetch 3 ahead (writes slot (t-1)&3, safe: readers crossed barrier)
      int pt = t + 3; if (pt > 63) pt = 63;
      stage(pt, (t + 3) & 3);

      const char* ab = Abuf[ks];
      s16x8 afr[4];
#pragma unroll
      for (int mf = 0; mf < 4; ++mf)
        afr[mf] = *reinterpret_cast<const s16x8*>(
            ab + (wm * 4 + mf) * 1024 + fofs);

      __builtin_amdgcn_s_setprio(1);
#pragma unroll
      for (int mf = 0; mf < 4; ++mf)
#pragma unroll
        for (int nf = 0; nf < 4; ++nf)
          P[mf][nf] = __builtin_amdgcn_mfma_f32_16x16x32_bf16(
              afr[mf], bfr[ks][nf], ks == 0 ? Z : P[mf][nf], 0, 0, 0);
      __builtin_amdgcn_s_setprio(0);
    }
    // fold group into acc: acc += fm[g,px] * P   (free: VALU pipe)
    float sn[4];
#pragma unroll
    for (int nf = 0; nf < 4; ++nf) sn[nf] = fmT[g][wn * 64 + nf * 16 + lc];
#pragma unroll
    for (int mf = 0; mf < 4; ++mf)
#pragma unroll
      for (int nf = 0; nf < 4; ++nf)
#pragma unroll
        for (int i = 0; i < 4; ++i)
          acc[mf][nf][i] += sn[nf] * P[mf][nf][i];
  }

  // drain remaining gload_lds before block can retire (LDS reuse safety)
  asm volatile("s_waitcnt vmcnt(0)" ::: "memory");

  // ---- epilogue: bias + store ----
  float* outb = out + (size_t)b * O_N * HW_N + px0;
#pragma unroll
  for (int mf = 0; mf < 4; ++mf) {
    int o0 = wm * 64 + mf * 16 + lk * 4;
#pragma unroll
    for (int i = 0; i < 4; ++i) {
      float bias = b2[o0 + i];
#pragma unroll
      for (int nf = 0; nf < 4; ++nf) {
        int px = wn * 64 + nf * 16 + lc;
        outb[(size_t)(o0 + i) * HW_N + px] = acc[mf][nf][i] + bias;
      }
    }
  }
}

extern "C" void kernel_launch(void* const* d_in, const int* in_sizes, int n_in,
                              void* d_out, int out_size, void* d_ws, size_t ws_size,
                              hipStream_t stream) {
  const float* x  = (const float*)d_in[0];
  const float* W1 = (const float*)d_in[1];
  const float* b1 = (const float*)d_in[2];
  const float* W2 = (const float*)d_in[3];
  const float* b2 = (const float*)d_in[4];
  float* out = (float*)d_out;
  char* w2t = (char*)d_ws;             // 1 MB tiled bf16 copy of W2

  w2cvt_k<<<256, 256, 0, stream>>>(W2, w2t);
  ccattn_main_k<<<256, 512, 0, stream>>>(x, W1, b1, w2t, b2, out);
}